// Round 2
// baseline (97.427 us; speedup 1.0000x reference)
//
#include <hip/hip_runtime.h>

// SeparationLoss: mean over B of sum_{i!=j} max(0, thr^2 - ||kp_i - kp_j||^2)
// B = 131072, J = 17, 3 floats per joint -> 51 floats per batch.
//
// Design: one wave per block (64 threads, 64 batches). Wave stages its own
// contiguous 64*51*4 = 13056 B slice global->LDS with float4 loads, then each
// thread computes one batch from LDS. Single-wave workgroup => __syncthreads
// is just a waitcnt (no s_barrier stall), and 8 blocks/CU interleave their
// stage/compute phases for free overlap.

#define NJ      17
#define KPF     51          // floats per batch (17*3)
#define BPB     64          // batches per block
#define THREADS 64

__global__ __launch_bounds__(THREADS)
void sep_loss_kernel(const float* __restrict__ kps,
                     float* __restrict__ out,
                     float scale /* 2/B */, float thr2) {
    __shared__ float lds[BPB * KPF];            // 13056 B

    const int tid = threadIdx.x;
    const long long b0 = (long long)blockIdx.x * BPB;

    // ---- Stage 64 batches (contiguous, 16B-aligned: b0*51*4 % 16 == 0) ----
    const float4* __restrict__ src4 =
        reinterpret_cast<const float4*>(kps + b0 * KPF);
    float4* dst4 = reinterpret_cast<float4*>(lds);
    const int n4 = BPB * KPF / 4;               // 816 float4s
    #pragma unroll
    for (int i = tid; i < n4; i += THREADS) dst4[i] = src4[i];
    __syncthreads();                             // 1-wave block: waitcnt only

    // ---- Each thread: one batch. Row stride 51 floats (odd) -> benign banking. ----
    float kp[KPF];
    const float* my = lds + tid * KPF;
    #pragma unroll
    for (int k = 0; k < KPF; ++k) kp[k] = my[k];

    // m_i = thr2/2 - ||kp_i||^2 ; pair value = max(0, m_i + m_j + 2*dot)
    float m[NJ];
    #pragma unroll
    for (int i = 0; i < NJ; ++i) {
        float x = kp[i * 3], y = kp[i * 3 + 1], z = kp[i * 3 + 2];
        m[i] = 0.5f * thr2 - fmaf(x, x, fmaf(y, y, z * z));
    }

    float acc = 0.0f;
    #pragma unroll
    for (int i = 0; i < NJ; ++i) {
        #pragma unroll
        for (int j = i + 1; j < NJ; ++j) {
            float dot = fmaf(kp[i * 3],     kp[j * 3],
                       fmaf(kp[i * 3 + 1], kp[j * 3 + 1],
                            kp[i * 3 + 2] * kp[j * 3 + 2]));
            float v = fmaf(2.0f, dot, m[i] + m[j]);
            acc += fmaxf(v, 0.0f);
        }
    }

    // ---- Wave-64 reduction, one atomic per block ----
    #pragma unroll
    for (int off = 32; off > 0; off >>= 1)
        acc += __shfl_down(acc, off, 64);
    if (tid == 0)
        atomicAdd(out, acc * scale);    // scale = 2/B (ordered pairs + mean)
}

extern "C" void kernel_launch(void* const* d_in, const int* in_sizes, int n_in,
                              void* d_out, int out_size, void* d_ws, size_t ws_size,
                              hipStream_t stream) {
    const float* kps = (const float*)d_in[0];
    float* out = (float*)d_out;

    const int B = in_sizes[0] / KPF;            // 131072
    const float thr2 = 0.1f * 0.1f;             // THRESHOLD^2
    const float scale = 2.0f / (float)B;

    // d_out is poisoned with 0xAA before every timed launch -> zero it.
    hipMemsetAsync(d_out, 0, out_size * sizeof(float), stream);

    const int grid = B / BPB;                   // 2048
    sep_loss_kernel<<<grid, THREADS, 0, stream>>>(kps, out, scale, thr2);
}

// Round 3
// 73.469 us; speedup vs baseline: 1.3261x; 1.3261x over previous
//
#include <hip/hip_runtime.h>

// SeparationLoss: mean over B of sum_{i!=j} max(0, thr^2 - ||kp_i - kp_j||^2)
// B = 131072, J = 17, 3 floats per joint -> 51 floats per batch.
//
// Two-pass, atomic-free:
//   pass 1: 512 blocks x 256 threads, 256 batches/block staged via LDS;
//           block partial -> plain store to d_ws[blockIdx] (overwrites poison).
//   pass 2: 1 block x 256 threads reduces 512 partials, stores mean to d_out.
// No atomicAdd (same-address RMW serializes at L2 across XCDs), no d_out memset.

#define NJ      17
#define KPF     51          // floats per batch (17*3)
#define BPB     256         // batches per block (pass 1)
#define THREADS 256
#define NPART   512         // pass-1 grid = B / BPB

__global__ __launch_bounds__(THREADS)
void sep_loss_partial(const float* __restrict__ kps,
                      float* __restrict__ partial,
                      float thr2) {
    __shared__ float lds[BPB * KPF];            // 52224 B
    __shared__ float wsum[THREADS / 64];

    const int tid = threadIdx.x;
    const long long b0 = (long long)blockIdx.x * BPB;

    // ---- Stage 256 batches (contiguous, 16B-aligned) ----
    const float4* __restrict__ src4 =
        reinterpret_cast<const float4*>(kps + b0 * KPF);
    float4* dst4 = reinterpret_cast<float4*>(lds);
    const int n4 = BPB * KPF / 4;               // 3264 float4s
    for (int i = tid; i < n4; i += THREADS) dst4[i] = src4[i];
    __syncthreads();

    // ---- One batch per thread; row stride 51 (odd) -> benign LDS banking ----
    float kp[KPF];
    const float* my = lds + tid * KPF;
    #pragma unroll
    for (int k = 0; k < KPF; ++k) kp[k] = my[k];

    // m_i = thr2/2 - ||kp_i||^2 ; pair value = max(0, m_i + m_j + 2*dot)
    float m[NJ];
    #pragma unroll
    for (int i = 0; i < NJ; ++i) {
        float x = kp[i * 3], y = kp[i * 3 + 1], z = kp[i * 3 + 2];
        m[i] = 0.5f * thr2 - fmaf(x, x, fmaf(y, y, z * z));
    }

    float acc = 0.0f;
    #pragma unroll
    for (int i = 0; i < NJ; ++i) {
        #pragma unroll
        for (int j = i + 1; j < NJ; ++j) {
            float dot = fmaf(kp[i * 3],     kp[j * 3],
                       fmaf(kp[i * 3 + 1], kp[j * 3 + 1],
                            kp[i * 3 + 2] * kp[j * 3 + 2]));
            acc += fmaxf(fmaf(2.0f, dot, m[i] + m[j]), 0.0f);
        }
    }

    // ---- Block reduction -> one plain store ----
    #pragma unroll
    for (int off = 32; off > 0; off >>= 1)
        acc += __shfl_down(acc, off, 64);
    if ((tid & 63) == 0) wsum[tid >> 6] = acc;
    __syncthreads();
    if (tid == 0) {
        float s = wsum[0] + wsum[1] + wsum[2] + wsum[3];
        partial[blockIdx.x] = s;
    }
}

__global__ __launch_bounds__(THREADS)
void sep_loss_final(const float* __restrict__ partial,
                    float* __restrict__ out,
                    float scale /* 2/B */) {
    __shared__ float wsum[THREADS / 64];
    const int tid = threadIdx.x;

    float acc = partial[tid] + partial[tid + THREADS];   // 512 partials
    #pragma unroll
    for (int off = 32; off > 0; off >>= 1)
        acc += __shfl_down(acc, off, 64);
    if ((tid & 63) == 0) wsum[tid >> 6] = acc;
    __syncthreads();
    if (tid == 0)
        out[0] = (wsum[0] + wsum[1] + wsum[2] + wsum[3]) * scale;
}

extern "C" void kernel_launch(void* const* d_in, const int* in_sizes, int n_in,
                              void* d_out, int out_size, void* d_ws, size_t ws_size,
                              hipStream_t stream) {
    const float* kps = (const float*)d_in[0];
    float* out = (float*)d_out;
    float* partial = (float*)d_ws;              // 512 floats of scratch

    const int B = in_sizes[0] / KPF;            // 131072
    const float thr2 = 0.1f * 0.1f;             // THRESHOLD^2
    const float scale = 2.0f / (float)B;

    const int grid = B / BPB;                   // 512
    sep_loss_partial<<<grid, THREADS, 0, stream>>>(kps, partial, thr2);
    sep_loss_final<<<1, THREADS, 0, stream>>>(partial, out, scale);
}